// Round 5
// baseline (261.419 us; speedup 1.0000x reference)
//
#include <hip/hip_runtime.h>

#define DIM 64
#define GPW 4    // 16-row groups per wave in gemm
#define BSHIFT 9
#define BSPAN 512      // nodes per bucket
#define MAXNB 512      // max buckets (N <= 262144; here N=200000 -> NB=391)

typedef __attribute__((ext_vector_type(8))) __bf16 bf16x8;
typedef __attribute__((ext_vector_type(4))) __bf16 bf16x4;
typedef __attribute__((ext_vector_type(8))) unsigned short u16x8;
typedef __attribute__((ext_vector_type(4))) float f32x4;

__device__ __forceinline__ f32x4 mfma16(bf16x8 a, bf16x8 b, f32x4 c) {
    return __builtin_amdgcn_mfma_f32_16x16x32_bf16(a, b, c, 0, 0, 0);
}

__device__ __forceinline__ float bf2f(unsigned short u) {
    return __uint_as_float((unsigned)u << 16);
}

// ---------- hierarchical CSR build (bucket -> node counting sort) ----------

__global__ void zerob_kernel(int* __restrict__ b) { b[threadIdx.x] = 0; }

__global__ __launch_bounds__(512) void bucket_count_kernel(
    const int* __restrict__ ei, int* __restrict__ bcnt, int E_, int NB) {
    __shared__ int hist[MAXNB];
    int tid = threadIdx.x;
    for (int i = tid; i < NB; i += 512) hist[i] = 0;
    __syncthreads();
    int chunk = (E_ + gridDim.x - 1) / gridDim.x;
    int e0 = blockIdx.x * chunk, e1 = min(E_, e0 + chunk);
    for (int e = e0 + tid; e < e1; e += 512)
        atomicAdd(&hist[ei[E_ + e] >> BSHIFT], 1);
    __syncthreads();
    for (int i = tid; i < NB; i += 512)
        if (hist[i]) atomicAdd(&bcnt[i], hist[i]);
}

__global__ __launch_bounds__(512) void bucket_scan_kernel(
    const int* __restrict__ bcnt, int* __restrict__ bptr, int* __restrict__ bcur,
    int* __restrict__ rowptr, int NB, int N_, int E_) {
    __shared__ int sm[512];
    int tid = threadIdx.x;
    int v = (tid < NB) ? bcnt[tid] : 0;
    sm[tid] = v;
    __syncthreads();
    for (int off = 1; off < 512; off <<= 1) {
        int t = 0;
        if (tid >= off) t = sm[tid - off];
        __syncthreads();
        if (tid >= off) sm[tid] += t;
        __syncthreads();
    }
    if (tid < NB) {
        int ex = sm[tid] - v;
        bptr[tid] = ex;
        bcur[tid] = ex;
    }
    if (tid == 0) { bptr[NB] = E_; rowptr[N_] = E_; }
}

__global__ __launch_bounds__(512) void scatter_kernel(
    const int* __restrict__ ei, int* __restrict__ bcur,
    unsigned* __restrict__ packed, int E_, int NB) {
    __shared__ int h[MAXNB];
    int tid = threadIdx.x;
    int chunk = (E_ + gridDim.x - 1) / gridDim.x;
    int e0 = blockIdx.x * chunk, e1 = min(E_, e0 + chunk);
    for (int i = tid; i < NB; i += 512) h[i] = 0;
    __syncthreads();
    for (int e = e0 + tid; e < e1; e += 512)
        atomicAdd(&h[ei[E_ + e] >> BSHIFT], 1);
    __syncthreads();
    for (int i = tid; i < NB; i += 512) {
        int c = h[i];
        h[i] = c ? atomicAdd(&bcur[i], c) : 0;
    }
    __syncthreads();
    for (int e = e0 + tid; e < e1; e += 512) {
        int s = ei[e], d = ei[E_ + e];
        int b = d >> BSHIFT;
        int pos = atomicAdd(&h[b], 1);
        packed[pos] = ((unsigned)s << BSHIFT) | (unsigned)(d & (BSPAN - 1));
    }
}

__global__ __launch_bounds__(256) void bucket_sort_kernel(
    const unsigned* __restrict__ packed, const int* __restrict__ bptr,
    int* __restrict__ rowptr, int* __restrict__ srcs,
    float* __restrict__ dinv, int N_) {
    __shared__ int cnt[BSPAN];
    __shared__ int sc[256];
    int tid = threadIdx.x;
    int b = blockIdx.x;
    int beg = bptr[b], end = bptr[b + 1];
    int node0 = b << BSHIFT;
    int nn = min(BSPAN, N_ - node0);
    cnt[tid] = 0; cnt[tid + 256] = 0;
    __syncthreads();
    for (int i = beg + tid; i < end; i += 256)
        atomicAdd(&cnt[packed[i] & (BSPAN - 1)], 1);
    __syncthreads();
    int degA = cnt[tid], degB = cnt[tid + 256];
    int a0 = cnt[2 * tid], a1 = cnt[2 * tid + 1];
    if (tid < nn) dinv[node0 + tid] = rsqrtf((float)(1 + degA));
    if (tid + 256 < nn) dinv[node0 + tid + 256] = rsqrtf((float)(1 + degB));
    int tot = a0 + a1;
    sc[tid] = tot;
    __syncthreads();
    for (int off = 1; off < 256; off <<= 1) {
        int t = 0;
        if (tid >= off) t = sc[tid - off];
        __syncthreads();
        if (tid >= off) sc[tid] += t;
        __syncthreads();
    }
    int ex = sc[tid] - tot;
    cnt[2 * tid] = ex;
    cnt[2 * tid + 1] = ex + a0;
    __syncthreads();
    if (tid < nn) rowptr[node0 + tid] = beg + cnt[tid];
    if (tid + 256 < nn) rowptr[node0 + tid + 256] = beg + cnt[tid + 256];
    __syncthreads();
    for (int i = beg + tid; i < end; i += 256) {
        unsigned p = packed[i];
        int pos = atomicAdd(&cnt[p & (BSPAN - 1)], 1);
        srcs[beg + pos] = (int)(p >> BSHIFT);
    }
}

// ---------- layer kernels ----------

// h'(bf16) = (x @ W1) * dinv[row].   MFMA 16x16x32 bf16. fp32 input.
// NT loads on the single-use 51 MB embedding read (keep L2 for h writes).
__global__ __launch_bounds__(256) void gemm_kernel(
    const float* __restrict__ xa_, const float* __restrict__ xb_, int split,
    const float* __restrict__ W, const float* __restrict__ dinv,
    __bf16* __restrict__ h, int n, int ngroups) {
    int lane = threadIdx.x & 63;
    int q = lane >> 4, t = lane & 15;
    int wv = __builtin_amdgcn_readfirstlane(threadIdx.x >> 6);
    int g0 = (blockIdx.x * 4 + wv) * GPW;
    if (g0 >= ngroups) return;

    bf16x8 Bf[4][2];
#pragma unroll
    for (int nt = 0; nt < 4; ++nt)
#pragma unroll
        for (int kt = 0; kt < 2; ++kt) {
            bf16x8 f;
#pragma unroll
            for (int j = 0; j < 8; ++j)
                f[j] = (__bf16)W[(kt * 32 + q * 8 + j) * DIM + nt * 16 + t];
            Bf[nt][kt] = f;
        }

    auto loadA = [&](int r0, f32x4* raw) {
        int row = r0 + t;
        if (row >= n) row = n - 1;
        const float* xr = (row < split)
            ? (xa_ + (size_t)row * DIM)
            : (xb_ + (size_t)(row - split) * DIM);
        raw[0] = __builtin_nontemporal_load((const f32x4*)(xr + q * 8));
        raw[1] = __builtin_nontemporal_load((const f32x4*)(xr + q * 8 + 4));
        raw[2] = __builtin_nontemporal_load((const f32x4*)(xr + 32 + q * 8));
        raw[3] = __builtin_nontemporal_load((const f32x4*)(xr + 32 + q * 8 + 4));
    };

    f32x4 cur[4];
    loadA(g0 * 16, cur);

#pragma unroll 1
    for (int gi = 0; gi < GPW; ++gi) {
        int g = g0 + gi;
        if (g >= ngroups) break;
        int r0 = g * 16;
        f32x4 nxt[4];
        bool pf = (gi + 1 < GPW) && (g + 1 < ngroups);
        if (pf) loadA(r0 + 16, nxt);

        bf16x8 A0, A1;
#pragma unroll
        for (int j = 0; j < 4; ++j) {
            A0[j] = (__bf16)cur[0][j]; A0[j + 4] = (__bf16)cur[1][j];
            A1[j] = (__bf16)cur[2][j]; A1[j + 4] = (__bf16)cur[3][j];
        }

        f32x4 z = {0.f, 0.f, 0.f, 0.f};
        f32x4 acc[4];
#pragma unroll
        for (int nt = 0; nt < 4; ++nt)
            acc[nt] = mfma16(A1, Bf[nt][1], mfma16(A0, Bf[nt][0], z));

        f32x4 d4 = *(const f32x4*)(dinv + r0 + q * 4);
#pragma unroll
        for (int nt = 0; nt < 4; ++nt)
#pragma unroll
            for (int reg = 0; reg < 4; ++reg) {
                int row = r0 + q * 4 + reg;
                if (row < n)
                    h[(size_t)row * DIM + nt * 16 + t] =
                        (__bf16)(acc[nt][reg] * d4[reg]);
            }
#pragma unroll
        for (int i = 0; i < 4; ++i) cur[i] = nxt[i];
    }
}

// Fused agg1 + gemm2: per block, aggregate 32 node-rows (R4 agg scheme:
// 8 nodes/wave, full row per 8-lane group, in-register accumulate), apply
// b1 + dinv, cast bf16 into an LDS tile [32][72] (144 B stride kills the
// ds_read_b128 same-bank pattern), barrier, then waves 0/1 run the old
// gemm2 MFMA tile (W2 frags in regs) and write h2 = (t1 @ W2)*dinv.
// Saves the 51.2 MB t1 HBM round-trip + one launch.
__global__ __launch_bounds__(256) void agg_gemm_kernel(
    const int* __restrict__ rowptr, const int* __restrict__ srcs,
    const __bf16* __restrict__ h, const float* __restrict__ b1,
    const float* __restrict__ W2, const float* __restrict__ dinv,
    __bf16* __restrict__ h2, int n) {
    __shared__ __bf16 rows[32][72];   // 144 B stride
    int lane = threadIdx.x & 63;
    int t8 = lane & 7;
    int wv = __builtin_amdgcn_readfirstlane(threadIdx.x >> 6);
    int q = lane >> 4, t = lane & 15;
    int lrow = wv * 8 + (lane >> 3);
    int node = blockIdx.x * 32 + lrow;
    int nd = (node < n) ? node : (n - 1);

    // W2 fragments (only matmul waves need them)
    bf16x8 Bf[4][2];
    if (wv < 2) {
#pragma unroll
        for (int nt = 0; nt < 4; ++nt)
#pragma unroll
            for (int kt = 0; kt < 2; ++kt) {
                bf16x8 f;
#pragma unroll
                for (int j = 0; j < 8; ++j)
                    f[j] = (__bf16)W2[(kt * 32 + q * 8 + j) * DIM + nt * 16 + t];
                Bf[nt][kt] = f;
            }
    }

    // ---- aggregation phase (all 4 waves, 8 nodes each) ----
    int beg = rowptr[nd], end = rowptr[nd + 1];
    u16x8 sv = *(const u16x8*)(h + (size_t)nd * DIM + t8 * 8);
    float acc[8];
#pragma unroll
    for (int j = 0; j < 8; ++j) acc[j] = bf2f(sv[j]);

    int i = beg;
    while (i < end) {
        int idx = i + t8;
        int sl = (idx < end) ? srcs[idx] : 0;
        u16x8 vv[8];
#pragma unroll
        for (int k = 0; k < 8; ++k) {
            int s = __shfl(sl, (lane & 56) | k);
            vv[k] = *(const u16x8*)(h + (size_t)s * DIM + t8 * 8);
        }
#pragma unroll
        for (int k = 0; k < 8; ++k)
            if (i + k < end) {
#pragma unroll
                for (int j = 0; j < 8; ++j) acc[j] += bf2f(vv[k][j]);
            }
        i += 8;
    }

    float dn = dinv[nd];
    f32x4 b0 = *(const f32x4*)(b1 + t8 * 8);
    f32x4 b1v = *(const f32x4*)(b1 + t8 * 8 + 4);
    bf16x8 o;
#pragma unroll
    for (int j = 0; j < 4; ++j) {
        o[j]     = (__bf16)fmaf(dn, acc[j],     b0[j]);
        o[j + 4] = (__bf16)fmaf(dn, acc[j + 4], b1v[j]);
    }
    *(bf16x8*)&rows[lrow][t8 * 8] = o;
    __syncthreads();

    // ---- matmul phase (waves 0,1: 16 rows each) ----
    if (wv < 2) {
        const __bf16* ap = &rows[wv * 16 + t][0];
        bf16x8 A0 = *(const bf16x8*)(ap + q * 8);
        bf16x8 A1 = *(const bf16x8*)(ap + 32 + q * 8);
        f32x4 z = {0.f, 0.f, 0.f, 0.f};
        f32x4 acc2[4];
#pragma unroll
        for (int nt = 0; nt < 4; ++nt)
            acc2[nt] = mfma16(A1, Bf[nt][1], mfma16(A0, Bf[nt][0], z));
        int gr0 = blockIdx.x * 32 + wv * 16;
        f32x4 d4 = *(const f32x4*)(dinv + gr0 + q * 4);
#pragma unroll
        for (int nt = 0; nt < 4; ++nt)
#pragma unroll
            for (int reg = 0; reg < 4; ++reg) {
                int row = gr0 + q * 4 + reg;
                if (row < n)
                    h2[(size_t)row * DIM + nt * 16 + t] =
                        (__bf16)(acc2[nt][reg] * d4[reg]);
            }
    }
}

// out[node] = b2 + dinv[node]*(h2[node] + sum_s h2[s]).  8 nodes/wave.
// NT stores: the 50 MB fp32 output is single-use — keep it out of L2 so
// h2 (25.6 MB) stays resident for the gather.
__global__ __launch_bounds__(256) void agg_kernel(
    const int* __restrict__ rowptr, const int* __restrict__ srcs,
    const __bf16* __restrict__ h, const float* __restrict__ bias,
    const float* __restrict__ dinv, float* __restrict__ out, int n) {
    int lane = threadIdx.x & 63;
    int t8 = lane & 7;
    int wv = threadIdx.x >> 6;
    int node = (blockIdx.x * 4 + wv) * 8 + (lane >> 3);
    bool alive = node < n;
    int nd = alive ? node : (n - 1);
    int beg = rowptr[nd], end = rowptr[nd + 1];

    u16x8 sv = *(const u16x8*)(h + (size_t)nd * DIM + t8 * 8);
    float acc[8];
#pragma unroll
    for (int j = 0; j < 8; ++j) acc[j] = bf2f(sv[j]);

    int i = beg;
    while (i < end) {
        int idx = i + t8;
        int sl = (idx < end) ? srcs[idx] : 0;
        u16x8 vv[8];
#pragma unroll
        for (int k = 0; k < 8; ++k) {
            int s = __shfl(sl, (lane & 56) | k);
            vv[k] = *(const u16x8*)(h + (size_t)s * DIM + t8 * 8);
        }
#pragma unroll
        for (int k = 0; k < 8; ++k)
            if (i + k < end) {
#pragma unroll
                for (int j = 0; j < 8; ++j) acc[j] += bf2f(vv[k][j]);
            }
        i += 8;
    }

    float dn = dinv[nd];
    f32x4 b0 = *(const f32x4*)(bias + t8 * 8);
    f32x4 b1 = *(const f32x4*)(bias + t8 * 8 + 4);
    if (alive) {
        f32x4 o0, o1;
#pragma unroll
        for (int j = 0; j < 4; ++j) {
            o0[j] = fmaf(dn, acc[j],     b0[j]);
            o1[j] = fmaf(dn, acc[j + 4], b1[j]);
        }
        float* op = out + (size_t)node * DIM + t8 * 8;
        __builtin_nontemporal_store(o0, (f32x4*)op);
        __builtin_nontemporal_store(o1, (f32x4*)(op + 4));
    }
}

static inline size_t align16(size_t x) { return (x + 15) & ~(size_t)15; }

extern "C" void kernel_launch(void* const* d_in, const int* in_sizes, int n_in,
                              void* d_out, int out_size, void* d_ws, size_t ws_size,
                              hipStream_t stream) {
    const int* ei         = (const int*)d_in[0];
    const float* user_emb = (const float*)d_in[1];
    const float* item_emb = (const float*)d_in[2];
    const float* W1 = (const float*)d_in[3];
    const float* b1 = (const float*)d_in[4];
    const float* W2 = (const float*)d_in[5];
    const float* b2 = (const float*)d_in[6];
    float* out = (float*)d_out;

    const int E_ = in_sizes[0] / 2;
    const int NU = in_sizes[1] / DIM;
    const int NI = in_sizes[2] / DIM;
    const int N_ = NU + NI;
    const int NB = (N_ + BSPAN - 1) >> BSHIFT;

    // workspace layout (16B-aligned)
    char* p = (char*)d_ws;
    int* srcs   = (int*)p;               p += align16((size_t)E_ * 4);
    __bf16* h   = (__bf16*)p;            p += align16((size_t)N_ * DIM * 2);
    __bf16* t1  = (__bf16*)p;            p += align16((size_t)N_ * DIM * 2);
    float* dinv = (float*)p;             p += align16((size_t)N_ * 4);
    int* rowptr = (int*)p;               p += align16((size_t)(N_ + 1) * 4);
    int* bcnt   = (int*)p;               p += align16((size_t)MAXNB * 4);
    int* bptr   = (int*)p;               p += align16((size_t)(MAXNB + 1) * 4);
    int* bcur   = (int*)p;               p += align16((size_t)MAXNB * 4);
    // packed edge buffer aliases t1: fully consumed by bucket_sort before
    // agg_gemm writes t1 (h2).
    unsigned* packed = (unsigned*)t1;

    zerob_kernel<<<1, MAXNB, 0, stream>>>(bcnt);
    bucket_count_kernel<<<256, 512, 0, stream>>>(ei, bcnt, E_, NB);
    bucket_scan_kernel<<<1, 512, 0, stream>>>(bcnt, bptr, bcur, rowptr, NB, N_, E_);
    scatter_kernel<<<256, 512, 0, stream>>>(ei, bcur, packed, E_, NB);
    bucket_sort_kernel<<<NB, 256, 0, stream>>>(packed, bptr, rowptr, srcs, dinv, N_);

    int NG = (N_ + 15) / 16;                       // 16-row groups
    int gblocks = (NG + 4 * GPW - 1) / (4 * GPW);  // 4 waves/block
    int ablocks = (N_ + 31) / 32;                  // 32 nodes/block (8/wave)

    // layer 1 transform
    gemm_kernel<<<gblocks, 256, 0, stream>>>(user_emb, item_emb, NU,
                                             W1, dinv, h, N_, NG);
    // layer 1 aggregate fused with layer 2 transform: h2 -> t1
    agg_gemm_kernel<<<ablocks, 256, 0, stream>>>(rowptr, srcs, h, b1, W2,
                                                 dinv, t1, N_);
    // layer 2 aggregate
    agg_kernel<<<ablocks, 256, 0, stream>>>(rowptr, srcs, t1, b2, dinv, out, N_);
}